// Round 1
// baseline (308.527 us; speedup 1.0000x reference)
//
#include <hip/hip_runtime.h>
#include <hip/hip_bf16.h>

typedef __bf16 bf16x8 __attribute__((ext_vector_type(8)));
typedef float  f32x4  __attribute__((ext_vector_type(4)));

constexpr int N_  = 8;
constexpr int TO_ = 1024;
constexpr int TI_ = 4096;
constexpr int H_  = 512;

// ---------------------------------------------------------------------------
// helpers
// ---------------------------------------------------------------------------
__device__ inline void split8(const float4& x0, const float4& x1,
                              bf16x8& h, bf16x8& l)
{
    float xs[8] = {x0.x, x0.y, x0.z, x0.w, x1.x, x1.y, x1.z, x1.w};
#pragma unroll
    for (int i = 0; i < 8; ++i) {
        __bf16 hh = (__bf16)xs[i];
        h[i] = hh;
        l[i] = (__bf16)(xs[i] - (float)hh);
    }
}

__device__ inline void cvt8(const float4& x0, const float4& x1, bf16x8& h)
{
    float xs[8] = {x0.x, x0.y, x0.z, x0.w, x1.x, x1.y, x1.z, x1.w};
#pragma unroll
    for (int i = 0; i < 8; ++i) h[i] = (__bf16)xs[i];
}

// ---------------------------------------------------------------------------
// K1: S[n, m, t] = sum_h Q[n,m,h] * V[n,t,h]   (split-bf16, 3 MFMA products)
// tile 128x128, BK=32, 4 waves (2x2), each wave 64x64 (4x4 16x16 frags)
// ---------------------------------------------------------------------------
constexpr int BM1 = 128, BN1 = 128, BK1 = 32, LP1 = BK1 + 8; // padded stride 40

__global__ __launch_bounds__(256, 2)
void qk_kernel(const float* __restrict__ Q, const float* __restrict__ V,
               float* __restrict__ S)
{
    __shared__ __bf16 Ah[BM1 * LP1];
    __shared__ __bf16 Al[BM1 * LP1];
    __shared__ __bf16 Bh[BN1 * LP1];
    __shared__ __bf16 Bl[BN1 * LP1];

    const int tt = blockIdx.x, mt = blockIdx.y, n = blockIdx.z;
    const float* Qb = Q + ((size_t)n * TO_ + (size_t)mt * BM1) * H_;
    const float* Vb = V + ((size_t)n * TI_ + (size_t)tt * BN1) * H_;

    const int tid  = threadIdx.x;
    const int lane = tid & 63, wave = tid >> 6;
    const int wr = wave >> 1, wc = wave & 1;

    const int srow = tid >> 2, scg = tid & 3; // staging: row, 8-float col group

    f32x4 acc[4][4] = {};

    for (int k0 = 0; k0 < H_; k0 += BK1) {
        __syncthreads();
#pragma unroll
        for (int half = 0; half < 2; ++half) {
            const int r = srow + half * 64;
            {
                const float4* src =
                    reinterpret_cast<const float4*>(Qb + (size_t)r * H_ + k0 + scg * 8);
                float4 x0 = src[0], x1 = src[1];
                bf16x8 hv, lv;
                split8(x0, x1, hv, lv);
                *reinterpret_cast<bf16x8*>(&Ah[r * LP1 + scg * 8]) = hv;
                *reinterpret_cast<bf16x8*>(&Al[r * LP1 + scg * 8]) = lv;
            }
            {
                const float4* src =
                    reinterpret_cast<const float4*>(Vb + (size_t)r * H_ + k0 + scg * 8);
                float4 x0 = src[0], x1 = src[1];
                bf16x8 hv, lv;
                split8(x0, x1, hv, lv);
                *reinterpret_cast<bf16x8*>(&Bh[r * LP1 + scg * 8]) = hv;
                *reinterpret_cast<bf16x8*>(&Bl[r * LP1 + scg * 8]) = lv;
            }
        }
        __syncthreads();

        bf16x8 ah[4], al[4], bh[4], bl[4];
        const int fr = lane & 15, fg = (lane >> 4) * 8;
#pragma unroll
        for (int m = 0; m < 4; ++m) {
            const int row = wr * 64 + m * 16 + fr;
            ah[m] = *reinterpret_cast<const bf16x8*>(&Ah[row * LP1 + fg]);
            al[m] = *reinterpret_cast<const bf16x8*>(&Al[row * LP1 + fg]);
        }
#pragma unroll
        for (int j = 0; j < 4; ++j) {
            const int row = wc * 64 + j * 16 + fr;
            bh[j] = *reinterpret_cast<const bf16x8*>(&Bh[row * LP1 + fg]);
            bl[j] = *reinterpret_cast<const bf16x8*>(&Bl[row * LP1 + fg]);
        }
#pragma unroll
        for (int m = 0; m < 4; ++m)
#pragma unroll
            for (int j = 0; j < 4; ++j) {
                acc[m][j] = __builtin_amdgcn_mfma_f32_16x16x32_bf16(ah[m], bh[j], acc[m][j], 0, 0, 0);
                acc[m][j] = __builtin_amdgcn_mfma_f32_16x16x32_bf16(ah[m], bl[j], acc[m][j], 0, 0, 0);
                acc[m][j] = __builtin_amdgcn_mfma_f32_16x16x32_bf16(al[m], bh[j], acc[m][j], 0, 0, 0);
            }
    }

    // C/D layout (m89): col = lane&15, row = (lane>>4)*4 + reg
    float* Sb = S + ((size_t)n * TO_ + (size_t)mt * BM1) * TI_ + (size_t)tt * BN1;
    const int crow0 = wr * 64 + (lane >> 4) * 4;
    const int ccol0 = wc * 64 + (lane & 15);
#pragma unroll
    for (int m = 0; m < 4; ++m)
#pragma unroll
        for (int j = 0; j < 4; ++j)
#pragma unroll
            for (int r = 0; r < 4; ++r)
                Sb[(size_t)(crow0 + m * 16 + r) * TI_ + (ccol0 + j * 16)] = acc[m][j][r];
}

// ---------------------------------------------------------------------------
// K2: in-place row softmax over Ti=4096. One wave per row, row in registers.
// ---------------------------------------------------------------------------
__global__ __launch_bounds__(256)
void softmax_kernel(float* __restrict__ S)
{
    const int wave = threadIdx.x >> 6, lane = threadIdx.x & 63;
    const size_t row = (size_t)blockIdx.x * 4 + wave;
    float4* p = reinterpret_cast<float4*>(S + row * TI_);

    float4 v[16];
    float m = -3.0e38f;
#pragma unroll
    for (int j = 0; j < 16; ++j) {
        v[j] = p[j * 64 + lane];
        m = fmaxf(m, fmaxf(fmaxf(v[j].x, v[j].y), fmaxf(v[j].z, v[j].w)));
    }
#pragma unroll
    for (int s = 32; s > 0; s >>= 1) m = fmaxf(m, __shfl_xor(m, s));

    constexpr float L2E = 1.4426950408889634f;
    float sum = 0.f;
#pragma unroll
    for (int j = 0; j < 16; ++j) {
        v[j].x = exp2f((v[j].x - m) * L2E);
        v[j].y = exp2f((v[j].y - m) * L2E);
        v[j].z = exp2f((v[j].z - m) * L2E);
        v[j].w = exp2f((v[j].w - m) * L2E);
        sum += (v[j].x + v[j].y) + (v[j].z + v[j].w);
    }
#pragma unroll
    for (int s = 32; s > 0; s >>= 1) sum += __shfl_xor(sum, s);

    const float inv = 1.0f / sum;
#pragma unroll
    for (int j = 0; j < 16; ++j) {
        v[j].x *= inv; v[j].y *= inv; v[j].z *= inv; v[j].w *= inv;
        p[j * 64 + lane] = v[j];
    }
}

// ---------------------------------------------------------------------------
// K3: out[n,m,h] = sum_t attn[n,m,t] * V[n,t,h]
// tile 128(m) x 64(h), BK=32(t). V staged LDS-transposed: Bsm[h][t].
// 4 waves 2x2, each wave 64x32 (4x2 frags).
// ---------------------------------------------------------------------------
constexpr int BM3 = 128, BN3 = 64, BK3 = 32, LP3 = BK3 + 8; // stride 40

__global__ __launch_bounds__(256, 2)
void pv_kernel(const float* __restrict__ A, const float* __restrict__ V,
               float* __restrict__ O)
{
    __shared__ __bf16 Asm[BM3 * LP3]; // [m][t]
    __shared__ __bf16 Bsm[BN3 * LP3]; // [h][t]  (transposed V tile)

    const int ht = blockIdx.x, mt = blockIdx.y, n = blockIdx.z;
    const float* Ab = A + ((size_t)n * TO_ + (size_t)mt * BM3) * TI_;
    const float* Vb = V + (size_t)n * TI_ * H_ + (size_t)ht * BN3;

    const int tid  = threadIdx.x;
    const int lane = tid & 63, wave = tid >> 6;
    const int wr = wave >> 1, wc = wave & 1;

    const int arow = tid >> 2, acg = tid & 3; // A staging
    const int bt = tid >> 3, bhg = tid & 7;   // B staging: t row, 8-h group

    f32x4 acc[4][2] = {};

    for (int k0 = 0; k0 < TI_; k0 += BK3) {
        __syncthreads();
#pragma unroll
        for (int half = 0; half < 2; ++half) {
            const int r = arow + half * 64;
            const float4* src =
                reinterpret_cast<const float4*>(Ab + (size_t)r * TI_ + k0 + acg * 8);
            float4 x0 = src[0], x1 = src[1];
            bf16x8 hv;
            cvt8(x0, x1, hv);
            *reinterpret_cast<bf16x8*>(&Asm[r * LP3 + acg * 8]) = hv;
        }
        {
            const float4* src =
                reinterpret_cast<const float4*>(Vb + (size_t)(k0 + bt) * H_ + bhg * 8);
            float4 x0 = src[0], x1 = src[1];
            float xs[8] = {x0.x, x0.y, x0.z, x0.w, x1.x, x1.y, x1.z, x1.w};
#pragma unroll
            for (int i = 0; i < 8; ++i)
                Bsm[(bhg * 8 + i) * LP3 + bt] = (__bf16)xs[i];
        }
        __syncthreads();

        bf16x8 a[4], b[2];
        const int fr = lane & 15, fg = (lane >> 4) * 8;
#pragma unroll
        for (int m = 0; m < 4; ++m)
            a[m] = *reinterpret_cast<const bf16x8*>(&Asm[(wr * 64 + m * 16 + fr) * LP3 + fg]);
#pragma unroll
        for (int j = 0; j < 2; ++j)
            b[j] = *reinterpret_cast<const bf16x8*>(&Bsm[(wc * 32 + j * 16 + fr) * LP3 + fg]);
#pragma unroll
        for (int m = 0; m < 4; ++m)
#pragma unroll
            for (int j = 0; j < 2; ++j)
                acc[m][j] = __builtin_amdgcn_mfma_f32_16x16x32_bf16(a[m], b[j], acc[m][j], 0, 0, 0);
    }

    float* Ob = O + ((size_t)n * TO_ + (size_t)mt * BM3) * H_ + (size_t)ht * BN3;
    const int crow0 = wr * 64 + (lane >> 4) * 4;
    const int ccol0 = wc * 32 + (lane & 15);
#pragma unroll
    for (int m = 0; m < 4; ++m)
#pragma unroll
        for (int j = 0; j < 2; ++j)
#pragma unroll
            for (int r = 0; r < 4; ++r)
                Ob[(size_t)(crow0 + m * 16 + r) * H_ + (ccol0 + j * 16)] = acc[m][j][r];
}

// ---------------------------------------------------------------------------
extern "C" void kernel_launch(void* const* d_in, const int* in_sizes, int n_in,
                              void* d_out, int out_size, void* d_ws, size_t ws_size,
                              hipStream_t stream)
{
    const float* Q = (const float*)d_in[0];
    const float* V = (const float*)d_in[1];
    float* out  = (float*)d_out;
    float* attn = out + (size_t)N_ * TO_ * H_; // second output region

    // S is computed into the attn region, softmaxed in place, then consumed.
    qk_kernel<<<dim3(TI_ / BN1, TO_ / BM1, N_), 256, 0, stream>>>(Q, V, attn);
    softmax_kernel<<<dim3(N_ * TO_ / 4), 256, 0, stream>>>(attn);
    pv_kernel<<<dim3(H_ / BN3, TO_ / BM3, N_), 256, 0, stream>>>(attn, V, out);
}

// Round 2
// 265.710 us; speedup vs baseline: 1.1611x; 1.1611x over previous
//
#include <hip/hip_runtime.h>
#include <hip/hip_bf16.h>

typedef __bf16 bf16x8 __attribute__((ext_vector_type(8)));
typedef __bf16 bf16x4 __attribute__((ext_vector_type(4)));
typedef float  f32x4  __attribute__((ext_vector_type(4)));

constexpr int N_  = 8;
constexpr int TO_ = 1024;
constexpr int TI_ = 4096;
constexpr int H_  = 512;

// ---------------------------------------------------------------------------
// helpers
// ---------------------------------------------------------------------------
__device__ inline void split8(const float4& x0, const float4& x1,
                              bf16x8& h, bf16x8& l)
{
    float xs[8] = {x0.x, x0.y, x0.z, x0.w, x1.x, x1.y, x1.z, x1.w};
#pragma unroll
    for (int i = 0; i < 8; ++i) {
        __bf16 hh = (__bf16)xs[i];
        h[i] = hh;
        l[i] = (__bf16)(xs[i] - (float)hh);
    }
}

__device__ inline void cvt8(const float4& x0, const float4& x1, bf16x8& h)
{
    float xs[8] = {x0.x, x0.y, x0.z, x0.w, x1.x, x1.y, x1.z, x1.w};
#pragma unroll
    for (int i = 0; i < 8; ++i) h[i] = (__bf16)xs[i];
}

// ---------------------------------------------------------------------------
// K1: S[n, m, t] = sum_h Q[n,m,h] * V[n,t,h]   (split-bf16, 3 MFMA products)
// tile 128x128, BK=32, 4 waves (2x2), each wave 64x64 (4x4 16x16 frags)
// ---------------------------------------------------------------------------
constexpr int BM1 = 128, BN1 = 128, BK1 = 32, LP1 = BK1 + 8; // padded stride 40

__global__ __launch_bounds__(256, 2)
void qk_kernel(const float* __restrict__ Q, const float* __restrict__ V,
               float* __restrict__ S)
{
    __shared__ __bf16 Ah[BM1 * LP1];
    __shared__ __bf16 Al[BM1 * LP1];
    __shared__ __bf16 Bh[BN1 * LP1];
    __shared__ __bf16 Bl[BN1 * LP1];

    const int tt = blockIdx.x, mt = blockIdx.y, n = blockIdx.z;
    const float* Qb = Q + ((size_t)n * TO_ + (size_t)mt * BM1) * H_;
    const float* Vb = V + ((size_t)n * TI_ + (size_t)tt * BN1) * H_;

    const int tid  = threadIdx.x;
    const int lane = tid & 63, wave = tid >> 6;
    const int wr = wave >> 1, wc = wave & 1;

    const int srow = tid >> 2, scg = tid & 3; // staging: row, 8-float col group

    f32x4 acc[4][4] = {};

    for (int k0 = 0; k0 < H_; k0 += BK1) {
        __syncthreads();
#pragma unroll
        for (int half = 0; half < 2; ++half) {
            const int r = srow + half * 64;
            {
                const float4* src =
                    reinterpret_cast<const float4*>(Qb + (size_t)r * H_ + k0 + scg * 8);
                float4 x0 = src[0], x1 = src[1];
                bf16x8 hv, lv;
                split8(x0, x1, hv, lv);
                *reinterpret_cast<bf16x8*>(&Ah[r * LP1 + scg * 8]) = hv;
                *reinterpret_cast<bf16x8*>(&Al[r * LP1 + scg * 8]) = lv;
            }
            {
                const float4* src =
                    reinterpret_cast<const float4*>(Vb + (size_t)r * H_ + k0 + scg * 8);
                float4 x0 = src[0], x1 = src[1];
                bf16x8 hv, lv;
                split8(x0, x1, hv, lv);
                *reinterpret_cast<bf16x8*>(&Bh[r * LP1 + scg * 8]) = hv;
                *reinterpret_cast<bf16x8*>(&Bl[r * LP1 + scg * 8]) = lv;
            }
        }
        __syncthreads();

        bf16x8 ah[4], al[4], bh[4], bl[4];
        const int fr = lane & 15, fg = (lane >> 4) * 8;
#pragma unroll
        for (int m = 0; m < 4; ++m) {
            const int row = wr * 64 + m * 16 + fr;
            ah[m] = *reinterpret_cast<const bf16x8*>(&Ah[row * LP1 + fg]);
            al[m] = *reinterpret_cast<const bf16x8*>(&Al[row * LP1 + fg]);
        }
#pragma unroll
        for (int j = 0; j < 4; ++j) {
            const int row = wc * 64 + j * 16 + fr;
            bh[j] = *reinterpret_cast<const bf16x8*>(&Bh[row * LP1 + fg]);
            bl[j] = *reinterpret_cast<const bf16x8*>(&Bl[row * LP1 + fg]);
        }
#pragma unroll
        for (int m = 0; m < 4; ++m)
#pragma unroll
            for (int j = 0; j < 4; ++j) {
                acc[m][j] = __builtin_amdgcn_mfma_f32_16x16x32_bf16(ah[m], bh[j], acc[m][j], 0, 0, 0);
                acc[m][j] = __builtin_amdgcn_mfma_f32_16x16x32_bf16(ah[m], bl[j], acc[m][j], 0, 0, 0);
                acc[m][j] = __builtin_amdgcn_mfma_f32_16x16x32_bf16(al[m], bh[j], acc[m][j], 0, 0, 0);
            }
    }

    // C/D layout: col = lane&15, row = (lane>>4)*4 + reg
    float* Sb = S + ((size_t)n * TO_ + (size_t)mt * BM1) * TI_ + (size_t)tt * BN1;
    const int crow0 = wr * 64 + (lane >> 4) * 4;
    const int ccol0 = wc * 64 + (lane & 15);
#pragma unroll
    for (int m = 0; m < 4; ++m)
#pragma unroll
        for (int j = 0; j < 4; ++j)
#pragma unroll
            for (int r = 0; r < 4; ++r)
                Sb[(size_t)(crow0 + m * 16 + r) * TI_ + (ccol0 + j * 16)] = acc[m][j][r];
}

// ---------------------------------------------------------------------------
// K2: in-place row softmax over Ti=4096. One wave per row, row in registers.
// ---------------------------------------------------------------------------
__global__ __launch_bounds__(256)
void softmax_kernel(float* __restrict__ S)
{
    const int wave = threadIdx.x >> 6, lane = threadIdx.x & 63;
    const size_t row = (size_t)blockIdx.x * 4 + wave;
    float4* p = reinterpret_cast<float4*>(S + row * TI_);

    float4 v[16];
    float m = -3.0e38f;
#pragma unroll
    for (int j = 0; j < 16; ++j) {
        v[j] = p[j * 64 + lane];
        m = fmaxf(m, fmaxf(fmaxf(v[j].x, v[j].y), fmaxf(v[j].z, v[j].w)));
    }
#pragma unroll
    for (int s = 32; s > 0; s >>= 1) m = fmaxf(m, __shfl_xor(m, s));

    constexpr float L2E = 1.4426950408889634f;
    float sum = 0.f;
#pragma unroll
    for (int j = 0; j < 16; ++j) {
        v[j].x = exp2f((v[j].x - m) * L2E);
        v[j].y = exp2f((v[j].y - m) * L2E);
        v[j].z = exp2f((v[j].z - m) * L2E);
        v[j].w = exp2f((v[j].w - m) * L2E);
        sum += (v[j].x + v[j].y) + (v[j].z + v[j].w);
    }
#pragma unroll
    for (int s = 32; s > 0; s >>= 1) sum += __shfl_xor(sum, s);

    const float inv = 1.0f / sum;
#pragma unroll
    for (int j = 0; j < 16; ++j) {
        v[j].x *= inv; v[j].y *= inv; v[j].z *= inv; v[j].w *= inv;
        p[j * 64 + lane] = v[j];
    }
}

// ---------------------------------------------------------------------------
// K_vt: Vt[n][h][t] = (bf16) V[n][t][h].  LDS-free transpose:
// coalesced 4B reads (lane = h), packed bf16x8 stores per (h, t0..t0+7).
// grid (H/64, TI/512, N), 256 threads. Block: h range 64, t range 512.
// ---------------------------------------------------------------------------
__global__ __launch_bounds__(256)
void vt_kernel(const float* __restrict__ V, __bf16* __restrict__ Vt)
{
    const int hb = blockIdx.x, tb = blockIdx.y, n = blockIdx.z;
    const int h  = hb * 64 + (threadIdx.x >> 2);
    const int tq = threadIdx.x & 3;
    const float* Vn = V + (size_t)n * TI_ * H_;
    __bf16* Vtn = Vt + (size_t)n * H_ * TI_;

#pragma unroll
    for (int j = 0; j < 16; ++j) {
        const int t0 = tb * 512 + tq * 128 + j * 8;
        bf16x8 o;
#pragma unroll
        for (int e = 0; e < 8; ++e)
            o[e] = (__bf16)Vn[(size_t)(t0 + e) * H_ + h];
        *reinterpret_cast<bf16x8*>(&Vtn[(size_t)h * TI_ + t0]) = o;
    }
}

// ---------------------------------------------------------------------------
// K3 (fast): out[n,m,:] = attn[n,m,:] @ V[n,:,:] using pre-transposed Vt.
// BM=32 (attn rows), BN=512 (full H -> attn read exactly once), BK=64.
// 512 threads = 8 waves, each wave owns h-slice wv*64..+63 (2x4 frags).
// grid (n=8, mt=32) -> flat%8 == n -> all blocks sharing Vt[n] on one XCD.
// Register prefetch of next tile (T14) hides global latency at 1 block/CU.
// ---------------------------------------------------------------------------
constexpr int PBM = 32, PBK = 64, PLP = PBK + 8; // stride 72 elems (144 B)

__global__ __launch_bounds__(512, 2)
void pv_fast_kernel(const float* __restrict__ A, const __bf16* __restrict__ Vt,
                    float* __restrict__ O)
{
    __shared__ __bf16 Asm[PBM * PLP];   //  4.6 KiB  [m][t]
    __shared__ __bf16 Bsm[512 * PLP];   // 73.7 KiB  [h][t]

    const int n = blockIdx.x, mt = blockIdx.y;
    const float*  Ab = A  + ((size_t)n * TO_ + (size_t)mt * PBM) * TI_;
    const __bf16* Vb = Vt + (size_t)n * H_ * TI_;

    const int tid = threadIdx.x, lane = tid & 63, wv = tid >> 6;

    // staging assignments
    const int ar = tid >> 4;            // 0..31   A row
    const int ac = (tid & 15) * 4;      // A col group (4 floats)
    const int bh = tid >> 3;            // 0..63 (+64*i)  B row
    const int bc = (tid & 7) * 8;       // B chunk (8 bf16)

    float4 aReg;
    bf16x8 bReg[8];

    auto loadTile = [&](int k0) {
        aReg = *reinterpret_cast<const float4*>(Ab + (size_t)ar * TI_ + k0 + ac);
#pragma unroll
        for (int i = 0; i < 8; ++i)
            bReg[i] = *reinterpret_cast<const bf16x8*>(
                Vb + (size_t)(bh + i * 64) * TI_ + k0 + bc);
    };

    f32x4 acc[2][4] = {};
    const int fr = lane & 15, fg = (lane >> 4) * 8;

    loadTile(0);
    constexpr int NT = TI_ / PBK;   // 64
    for (int kt = 0; kt < NT; ++kt) {
        __syncthreads();
        {
            bf16x4 av;
            av[0] = (__bf16)aReg.x; av[1] = (__bf16)aReg.y;
            av[2] = (__bf16)aReg.z; av[3] = (__bf16)aReg.w;
            *reinterpret_cast<bf16x4*>(&Asm[ar * PLP + ac]) = av;
#pragma unroll
            for (int i = 0; i < 8; ++i)
                *reinterpret_cast<bf16x8*>(&Bsm[(bh + i * 64) * PLP + bc]) = bReg[i];
        }
        __syncthreads();
        if (kt + 1 < NT) loadTile((kt + 1) * PBK);   // issue early, wait later

#pragma unroll
        for (int kk = 0; kk < 2; ++kk) {
            bf16x8 af[2], bf[4];
#pragma unroll
            for (int m = 0; m < 2; ++m)
                af[m] = *reinterpret_cast<const bf16x8*>(
                    &Asm[(m * 16 + fr) * PLP + kk * 32 + fg]);
#pragma unroll
            for (int j = 0; j < 4; ++j)
                bf[j] = *reinterpret_cast<const bf16x8*>(
                    &Bsm[(wv * 64 + j * 16 + fr) * PLP + kk * 32 + fg]);
#pragma unroll
            for (int m = 0; m < 2; ++m)
#pragma unroll
                for (int j = 0; j < 4; ++j)
                    acc[m][j] = __builtin_amdgcn_mfma_f32_16x16x32_bf16(
                        af[m], bf[j], acc[m][j], 0, 0, 0);
        }
    }

    float* Ob = O + ((size_t)n * TO_ + (size_t)mt * PBM) * H_ + wv * 64;
    const int crow = (lane >> 4) * 4;
    const int ccol = lane & 15;
#pragma unroll
    for (int m = 0; m < 2; ++m)
#pragma unroll
        for (int j = 0; j < 4; ++j)
#pragma unroll
            for (int r = 0; r < 4; ++r)
                Ob[(size_t)(m * 16 + crow + r) * H_ + j * 16 + ccol] = acc[m][j][r];
}

// ---------------------------------------------------------------------------
// K3 (fallback, ws too small): original pv with in-LDS transpose.
// ---------------------------------------------------------------------------
constexpr int BM3 = 128, BN3 = 64, BK3 = 32, LP3 = BK3 + 8; // stride 40

__global__ __launch_bounds__(256, 2)
void pv_kernel(const float* __restrict__ A, const float* __restrict__ V,
               float* __restrict__ O)
{
    __shared__ __bf16 Asm[BM3 * LP3]; // [m][t]
    __shared__ __bf16 Bsm[BN3 * LP3]; // [h][t]  (transposed V tile)

    const int ht = blockIdx.x, mt = blockIdx.y, n = blockIdx.z;
    const float* Ab = A + ((size_t)n * TO_ + (size_t)mt * BM3) * TI_;
    const float* Vb = V + (size_t)n * TI_ * H_ + (size_t)ht * BN3;

    const int tid  = threadIdx.x;
    const int lane = tid & 63, wave = tid >> 6;
    const int wr = wave >> 1, wc = wave & 1;

    const int arow = tid >> 2, acg = tid & 3; // A staging
    const int bt = tid >> 3, bhg = tid & 7;   // B staging: t row, 8-h group

    f32x4 acc[4][2] = {};

    for (int k0 = 0; k0 < TI_; k0 += BK3) {
        __syncthreads();
#pragma unroll
        for (int half = 0; half < 2; ++half) {
            const int r = arow + half * 64;
            const float4* src =
                reinterpret_cast<const float4*>(Ab + (size_t)r * TI_ + k0 + acg * 8);
            float4 x0 = src[0], x1 = src[1];
            bf16x8 hv;
            cvt8(x0, x1, hv);
            *reinterpret_cast<bf16x8*>(&Asm[r * LP3 + acg * 8]) = hv;
        }
        {
            const float4* src =
                reinterpret_cast<const float4*>(Vb + (size_t)(k0 + bt) * H_ + bhg * 8);
            float4 x0 = src[0], x1 = src[1];
            float xs[8] = {x0.x, x0.y, x0.z, x0.w, x1.x, x1.y, x1.z, x1.w};
#pragma unroll
            for (int i = 0; i < 8; ++i)
                Bsm[(bhg * 8 + i) * LP3 + bt] = (__bf16)xs[i];
        }
        __syncthreads();

        bf16x8 a[4], b[2];
        const int fr = lane & 15, fg = (lane >> 4) * 8;
#pragma unroll
        for (int m = 0; m < 4; ++m)
            a[m] = *reinterpret_cast<const bf16x8*>(&Asm[(wr * 64 + m * 16 + fr) * LP3 + fg]);
#pragma unroll
        for (int j = 0; j < 2; ++j)
            b[j] = *reinterpret_cast<const bf16x8*>(&Bsm[(wc * 32 + j * 16 + fr) * LP3 + fg]);
#pragma unroll
        for (int m = 0; m < 4; ++m)
#pragma unroll
            for (int j = 0; j < 2; ++j)
                acc[m][j] = __builtin_amdgcn_mfma_f32_16x16x32_bf16(a[m], b[j], acc[m][j], 0, 0, 0);
    }

    float* Ob = O + ((size_t)n * TO_ + (size_t)mt * BM3) * H_ + (size_t)ht * BN3;
    const int crow0 = wr * 64 + (lane >> 4) * 4;
    const int ccol0 = wc * 32 + (lane & 15);
#pragma unroll
    for (int m = 0; m < 4; ++m)
#pragma unroll
        for (int j = 0; j < 2; ++j)
#pragma unroll
            for (int r = 0; r < 4; ++r)
                Ob[(size_t)(crow0 + m * 16 + r) * H_ + (ccol0 + j * 16)] = acc[m][j][r];
}

// ---------------------------------------------------------------------------
extern "C" void kernel_launch(void* const* d_in, const int* in_sizes, int n_in,
                              void* d_out, int out_size, void* d_ws, size_t ws_size,
                              hipStream_t stream)
{
    const float* Q = (const float*)d_in[0];
    const float* V = (const float*)d_in[1];
    float* out  = (float*)d_out;
    float* attn = out + (size_t)N_ * TO_ * H_; // second output region

    const size_t VT_BYTES = (size_t)N_ * H_ * TI_ * sizeof(__bf16); // 32 MiB
    const bool fast = (ws_size >= VT_BYTES);

    if (fast)
        vt_kernel<<<dim3(H_ / 64, TI_ / 512, N_), 256, 0, stream>>>(V, (__bf16*)d_ws);

    qk_kernel<<<dim3(TI_ / BN1, TO_ / BM1, N_), 256, 0, stream>>>(Q, V, attn);
    softmax_kernel<<<dim3(N_ * TO_ / 4), 256, 0, stream>>>(attn);

    if (fast)
        pv_fast_kernel<<<dim3(N_, TO_ / PBM), 512, 0, stream>>>(attn, (const __bf16*)d_ws, out);
    else
        pv_kernel<<<dim3(H_ / BN3, TO_ / BM3, N_), 256, 0, stream>>>(attn, V, out);
}